// Round 1
// baseline (17380.731 us; speedup 1.0000x reference)
//
#include <hip/hip_runtime.h>
#include <math.h>

// ---------------------------------------------------------------------------
// Variance-propagating UNet (density prop), fp32, NHWC.
// Round 0: correctness-first implementation.
// ---------------------------------------------------------------------------

__device__ __forceinline__ float softplus_f(float x) { return log1pf(expf(x)); }

// First layer: mu = conv3x3(pad(x), w_mu); s = (patch-sum of x^2) * softplus(w_sig[co]); relu.
// x: [B,H,W,Cin]; out: [B,H,W,Cout]
__global__ void conv_input_relu_kernel(const float* __restrict__ x,
                                       const float* __restrict__ w_mu,
                                       const float* __restrict__ w_sig,
                                       float* __restrict__ mu_out,
                                       float* __restrict__ s_out,
                                       int B, int H, int W, int Cin, int Cout)
{
    int co  = threadIdx.x;
    int pix = blockIdx.x * blockDim.y + threadIdx.y;
    int total = B * H * W;
    if (pix >= total) return;
    int b = pix / (H * W);
    int rem = pix % (H * W);
    int h = rem / W, w = rem % W;

    float mu = 0.f, q = 0.f;
    for (int kh = 0; kh < 3; kh++) {
        int ih = h + kh - 1;
        if (ih < 0 || ih >= H) continue;
        for (int kw = 0; kw < 3; kw++) {
            int iw = w + kw - 1;
            if (iw < 0 || iw >= W) continue;
            const float* xp = x + ((size_t)(b * H + ih) * W + iw) * Cin;
            const float* wp = w_mu + (size_t)((kh * 3 + kw) * Cin) * Cout + co;
            for (int ci = 0; ci < Cin; ci++) {
                float xv = xp[ci];
                mu += xv * wp[(size_t)ci * Cout];
                q  += xv * xv;
            }
        }
    }
    float s = q * softplus_f(w_sig[co]);
    if (!(mu > 0.f)) { mu = 0.f; s = 0.f; }   // relu + grad mask
    size_t oidx = (size_t)pix * Cout + co;
    mu_out[oidx] = mu;
    s_out[oidx]  = s;
}

// q[b,h,w] = sum over 3x3 patch, all cin of (mu^2 + s). pad in {0,1}.
__global__ void patch_q_kernel(const float* __restrict__ mu_in,
                               const float* __restrict__ s_in,
                               float* __restrict__ q_out,
                               int B, int Hin, int Win, int Cin,
                               int Hout, int Wout, int pad)
{
    int pix = blockIdx.x * blockDim.x + threadIdx.x;
    int total = B * Hout * Wout;
    if (pix >= total) return;
    int b = pix / (Hout * Wout);
    int rem = pix % (Hout * Wout);
    int h = rem / Wout, w = rem % Wout;

    float q = 0.f;
    for (int kh = 0; kh < 3; kh++) {
        int ih = h + kh - pad;
        if (ih < 0 || ih >= Hin) continue;
        for (int kw = 0; kw < 3; kw++) {
            int iw = w + kw - pad;
            if (iw < 0 || iw >= Win) continue;
            size_t base = ((size_t)(b * Hin + ih) * Win + iw) * Cin;
            const float* mp = mu_in + base;
            const float* sp = s_in + base;
            for (int ci = 0; ci < Cin; ci++) {
                float m = mp[ci];
                q += m * m + sp[ci];
            }
        }
    }
    q_out[pix] = q;
}

// mu = conv3x3(mu_in, w_mu); s = q*softplus(w_sig[co]) + conv3x3(s_in, w_mu^2); optional relu.
__global__ void conv_inter_kernel(const float* __restrict__ mu_in,
                                  const float* __restrict__ s_in,
                                  const float* __restrict__ q,
                                  const float* __restrict__ w_mu,
                                  const float* __restrict__ w_sig,
                                  float* __restrict__ mu_out,
                                  float* __restrict__ s_out,
                                  int B, int Hin, int Win, int Cin,
                                  int Hout, int Wout, int Cout,
                                  int pad, int do_relu)
{
    int co  = threadIdx.x;
    int pix = blockIdx.x * blockDim.y + threadIdx.y;
    int total = B * Hout * Wout;
    if (pix >= total) return;
    int b = pix / (Hout * Wout);
    int rem = pix % (Hout * Wout);
    int h = rem / Wout, w = rem % Wout;

    float mu = 0.f, sa = 0.f;
    for (int kh = 0; kh < 3; kh++) {
        int ih = h + kh - pad;
        if (ih < 0 || ih >= Hin) continue;
        for (int kw = 0; kw < 3; kw++) {
            int iw = w + kw - pad;
            if (iw < 0 || iw >= Win) continue;
            size_t base = ((size_t)(b * Hin + ih) * Win + iw) * Cin;
            const float* mp = mu_in + base;
            const float* sp = s_in + base;
            const float* wp = w_mu + (size_t)((kh * 3 + kw) * Cin) * Cout + co;
            for (int ci = 0; ci < Cin; ci++) {
                float wv = wp[(size_t)ci * Cout];
                mu += mp[ci] * wv;
                sa += sp[ci] * (wv * wv);
            }
        }
    }
    float s = q[pix] * softplus_f(w_sig[co]) + sa;
    if (do_relu && !(mu > 0.f)) { mu = 0.f; s = 0.f; }
    size_t oidx = (size_t)pix * Cout + co;
    mu_out[oidx] = mu;
    s_out[oidx]  = s;
}

// 2x2/stride-2 argmax pool (first max; order (0,0),(0,1),(1,0),(1,1)); gather s at argmax.
__global__ void pool_kernel(const float* __restrict__ mu_in,
                            const float* __restrict__ s_in,
                            float* __restrict__ mu_out,
                            float* __restrict__ s_out,
                            int B, int H, int W, int C)
{
    int Ho = H / 2, Wo = W / 2;
    size_t total = (size_t)B * Ho * Wo * C;
    size_t idx = (size_t)blockIdx.x * blockDim.x + threadIdx.x;
    if (idx >= total) return;
    int c = idx % C;
    size_t t = idx / C;
    int w = t % Wo; t /= Wo;
    int h = t % Ho;
    int b = t / Ho;
    size_t i0 = ((size_t)(b * H + 2 * h) * W + 2 * w) * C + c;
    size_t rowStride = (size_t)W * C;
    float m00 = mu_in[i0], m01 = mu_in[i0 + C];
    float m10 = mu_in[i0 + rowStride], m11 = mu_in[i0 + rowStride + C];
    int best = 0; float bm = m00;
    if (m01 > bm) { bm = m01; best = 1; }
    if (m10 > bm) { bm = m10; best = 2; }
    if (m11 > bm) { bm = m11; best = 3; }
    size_t off = (size_t)(best >> 1) * rowStride + (size_t)(best & 1) * C;
    mu_out[idx] = bm;
    s_out[idx]  = s_in[i0 + off];
}

// zero-insertion unpool: out[b,2i+1,2j+1,c] = in[b,i,j,c]; out [B,2H+1,2W+1,C]
__global__ void unpool_kernel(const float* __restrict__ in,
                              float* __restrict__ out,
                              int B, int H, int W, int C)
{
    int Ho = 2 * H + 1, Wo = 2 * W + 1;
    size_t total = (size_t)B * Ho * Wo * C;
    size_t idx = (size_t)blockIdx.x * blockDim.x + threadIdx.x;
    if (idx >= total) return;
    int c = idx % C;
    size_t t = idx / C;
    int w = t % Wo; t /= Wo;
    int h = t % Ho;
    int b = t / Ho;
    float v = 0.f;
    if ((h & 1) && (w & 1))
        v = in[((size_t)(b * H + (h >> 1)) * W + (w >> 1)) * C + c];
    out[idx] = v;
}

// channel concat: out[...,0:Cd)=dec, out[...,Cd:Cd+Ce)=enc[b, h+dh, w+dw, :]
__global__ void concat_kernel(const float* __restrict__ dec,
                              const float* __restrict__ enc,
                              float* __restrict__ out,
                              int B, int H, int W, int Cd, int Ce,
                              int Henc, int Wenc, int dh, int dw)
{
    int C = Cd + Ce;
    size_t total = (size_t)B * H * W * C;
    size_t idx = (size_t)blockIdx.x * blockDim.x + threadIdx.x;
    if (idx >= total) return;
    int c = idx % C;
    size_t t = idx / C;
    int w = t % W; t /= W;
    int h = t % H;
    int b = t / H;
    float v;
    if (c < Cd)
        v = dec[((size_t)(b * H + h) * W + w) * Cd + c];
    else
        v = enc[((size_t)(b * Henc + h + dh) * Wenc + (w + dw)) * Ce + (c - Cd)];
    out[idx] = v;
}

// 1x1 conv_inter (Cin -> 2, no relu) fused with C=2 softmax density propagation.
// out: [p (B*H*W*2 floats)] then [s_out (B*H*W*2 floats)]
__global__ void final_kernel(const float* __restrict__ mu_in,
                             const float* __restrict__ s_in,
                             const float* __restrict__ w_mu,
                             const float* __restrict__ w_sig,
                             float* __restrict__ out,
                             int B, int H, int W, int Cin)
{
    int pix = blockIdx.x * blockDim.x + threadIdx.x;
    int total = B * H * W;
    if (pix >= total) return;
    const float* mp = mu_in + (size_t)pix * Cin;
    const float* sp = s_in + (size_t)pix * Cin;
    float mu0 = 0.f, mu1 = 0.f, s0a = 0.f, s1a = 0.f, q = 0.f;
    for (int ci = 0; ci < Cin; ci++) {
        float m = mp[ci], s = sp[ci];
        float w0 = w_mu[ci * 2], w1 = w_mu[ci * 2 + 1];
        mu0 += m * w0; mu1 += m * w1;
        s0a += s * (w0 * w0); s1a += s * (w1 * w1);
        q += m * m + s;
    }
    float s0 = q * softplus_f(w_sig[0]) + s0a;
    float s1 = q * softplus_f(w_sig[1]) + s1a;
    float mx = fmaxf(mu0, mu1);
    float e0 = expf(mu0 - mx), e1 = expf(mu1 - mx);
    float inv = 1.f / (e0 + e1);
    float p0 = e0 * inv, p1 = e1 * inv;
    float g00 = p0 - p0 * p0, g01 = -p0 * p1;
    float g10 = -p1 * p0,     g11 = p1 - p1 * p1;
    float so0 = g00 * g00 * s0 + g01 * g01 * s1;
    float so1 = g10 * g10 * s0 + g11 * g11 * s1;
    out[(size_t)pix * 2]     = p0;
    out[(size_t)pix * 2 + 1] = p1;
    size_t off = (size_t)total * 2;
    out[off + (size_t)pix * 2]     = so0;
    out[off + (size_t)pix * 2 + 1] = so1;
}

// ---------------------------------------------------------------------------

extern "C" void kernel_launch(void* const* d_in, const int* in_sizes, int n_in,
                              void* d_out, int out_size, void* d_ws, size_t ws_size,
                              hipStream_t stream)
{
    const float* x = (const float*)d_in[0];
    // weight order follows _SHAPES
    enum { E1A, E1B, E2A, E2B, BA, BB, D2U, D2A, D2B, D1U, D1A, D1B, FIN, NW };
    const float* wmu[NW];
    const float* wsig[NW];
    for (int i = 0; i < NW; i++) {
        wmu[i]  = (const float*)d_in[1 + 2 * i];
        wsig[i] = (const float*)d_in[2 + 2 * i];
    }

    const int B = 4;
    // workspace layout (floats)
    const size_t BUFSZ = 8258048;             // max tensor: 4*127*127*128
    float* ws = (float*)d_ws;
    float* Amu = ws;
    float* As  = ws + BUFSZ;
    float* Bmu = ws + 2 * BUFSZ;
    float* Bs  = ws + 3 * BUFSZ;
    float* E1mu = ws + 4 * BUFSZ;             // 4*128*128*64 = 4194304
    float* E1s  = E1mu + 4194304;
    float* E2mu = E1s + 4194304;              // 4*64*64*128 = 2097152
    float* E2s  = E2mu + 2097152;
    float* qbuf = E2s + 2097152;              // up to 4*128*128 = 65536

    auto launch_conv = [&](const float* mi, const float* si,
                           int hi, int wi, int ci,
                           int ho, int wo, int co,
                           int pad, int relu, int widx,
                           float* mo, float* so) {
        int totalPix = B * ho * wo;
        patch_q_kernel<<<dim3((totalPix + 255) / 256), dim3(256), 0, stream>>>(
            mi, si, qbuf, B, hi, wi, ci, ho, wo, pad);
        dim3 blk(co, 4);
        dim3 grd((totalPix + 3) / 4);
        conv_inter_kernel<<<grd, blk, 0, stream>>>(
            mi, si, qbuf, wmu[widx], wsig[widx], mo, so,
            B, hi, wi, ci, ho, wo, co, pad, relu);
    };

    // ---- encoder level 1 ----
    {
        int totalPix = B * 128 * 128;
        conv_input_relu_kernel<<<dim3((totalPix + 3) / 4), dim3(64, 4), 0, stream>>>(
            x, wmu[E1A], wsig[E1A], Amu, As, B, 128, 128, 3, 64);
    }
    launch_conv(Amu, As, 128, 128, 64, 128, 128, 64, 1, 1, E1B, E1mu, E1s);
    {
        size_t total = (size_t)B * 64 * 64 * 64;
        pool_kernel<<<dim3((total + 255) / 256), dim3(256), 0, stream>>>(
            E1mu, E1s, Amu, As, B, 128, 128, 64);
    }
    // ---- encoder level 2 ----
    launch_conv(Amu, As, 64, 64, 64, 64, 64, 128, 1, 1, E2A, Bmu, Bs);
    launch_conv(Bmu, Bs, 64, 64, 128, 64, 64, 128, 1, 1, E2B, E2mu, E2s);
    {
        size_t total = (size_t)B * 32 * 32 * 128;
        pool_kernel<<<dim3((total + 255) / 256), dim3(256), 0, stream>>>(
            E2mu, E2s, Amu, As, B, 64, 64, 128);
    }
    // ---- bottleneck ----
    launch_conv(Amu, As, 32, 32, 128, 32, 32, 256, 1, 1, BA, Bmu, Bs);
    launch_conv(Bmu, Bs, 32, 32, 256, 32, 32, 256, 1, 1, BB, Amu, As);
    // ---- decoder level 2 ----
    {
        size_t total = (size_t)B * 65 * 65 * 256;
        unpool_kernel<<<dim3((total + 255) / 256), dim3(256), 0, stream>>>(
            Amu, Bmu, B, 32, 32, 256);
        unpool_kernel<<<dim3((total + 255) / 256), dim3(256), 0, stream>>>(
            As, Bs, B, 32, 32, 256);
    }
    launch_conv(Bmu, Bs, 65, 65, 256, 63, 63, 128, 0, 1, D2U, Amu, As);
    {
        size_t total = (size_t)B * 63 * 63 * 256;
        concat_kernel<<<dim3((total + 255) / 256), dim3(256), 0, stream>>>(
            Amu, E2mu, Bmu, B, 63, 63, 128, 128, 64, 64, 0, 0);
        concat_kernel<<<dim3((total + 255) / 256), dim3(256), 0, stream>>>(
            As, E2s, Bs, B, 63, 63, 128, 128, 64, 64, 0, 0);
    }
    launch_conv(Bmu, Bs, 63, 63, 256, 63, 63, 128, 1, 1, D2A, Amu, As);
    launch_conv(Amu, As, 63, 63, 128, 63, 63, 128, 1, 1, D2B, Bmu, Bs);
    // ---- decoder level 1 ----
    {
        size_t total = (size_t)B * 127 * 127 * 128;
        unpool_kernel<<<dim3((total + 255) / 256), dim3(256), 0, stream>>>(
            Bmu, Amu, B, 63, 63, 128);
        unpool_kernel<<<dim3((total + 255) / 256), dim3(256), 0, stream>>>(
            Bs, As, B, 63, 63, 128);
    }
    launch_conv(Amu, As, 127, 127, 128, 125, 125, 64, 0, 1, D1U, Bmu, Bs);
    {
        size_t total = (size_t)B * 125 * 125 * 128;
        concat_kernel<<<dim3((total + 255) / 256), dim3(256), 0, stream>>>(
            Bmu, E1mu, Amu, B, 125, 125, 64, 64, 128, 128, 1, 1);
        concat_kernel<<<dim3((total + 255) / 256), dim3(256), 0, stream>>>(
            Bs, E1s, As, B, 125, 125, 64, 64, 128, 128, 1, 1);
    }
    launch_conv(Amu, As, 125, 125, 128, 125, 125, 64, 1, 1, D1A, Bmu, Bs);
    launch_conv(Bmu, Bs, 125, 125, 64, 125, 125, 64, 1, 1, D1B, Amu, As);
    // ---- final 1x1 + softmax prop ----
    {
        int totalPix = B * 125 * 125;
        final_kernel<<<dim3((totalPix + 255) / 256), dim3(256), 0, stream>>>(
            Amu, As, wmu[FIN], wsig[FIN], (float*)d_out, B, 125, 125, 64);
    }
}

// Round 2
// 4822.184 us; speedup vs baseline: 3.6043x; 3.6043x over previous
//
#include <hip/hip_runtime.h>
#include <math.h>

// ---------------------------------------------------------------------------
// Variance-propagating UNet (density prop), fp32, NHWC.
// Round 1: fuse q into conv (kill patch_q), 4 co/thread + ci x4 float4
// vectorization, fuse unpool into the d2u/d1u convs (parity tap lists).
// ---------------------------------------------------------------------------

__device__ __forceinline__ float softplus_f(float x) { return log1pf(expf(x)); }

// First layer: mu = conv3x3(pad(x), w_mu); s = (patch-sum of x^2) * softplus(w_sig[co]); relu.
__global__ void conv_input_relu_kernel(const float* __restrict__ x,
                                       const float* __restrict__ w_mu,
                                       const float* __restrict__ w_sig,
                                       float* __restrict__ mu_out,
                                       float* __restrict__ s_out,
                                       int B, int H, int W, int Cin, int Cout)
{
    int co  = threadIdx.x;
    int pix = blockIdx.x * blockDim.y + threadIdx.y;
    int total = B * H * W;
    if (pix >= total) return;
    int b = pix / (H * W);
    int rem = pix % (H * W);
    int h = rem / W, w = rem % W;

    float mu = 0.f, q = 0.f;
    for (int kh = 0; kh < 3; kh++) {
        int ih = h + kh - 1;
        if (ih < 0 || ih >= H) continue;
        for (int kw = 0; kw < 3; kw++) {
            int iw = w + kw - 1;
            if (iw < 0 || iw >= W) continue;
            const float* xp = x + ((size_t)(b * H + ih) * W + iw) * Cin;
            const float* wp = w_mu + (size_t)((kh * 3 + kw) * Cin) * Cout + co;
            for (int ci = 0; ci < Cin; ci++) {
                float xv = xp[ci];
                mu += xv * wp[(size_t)ci * Cout];
                q  += xv * xv;
            }
        }
    }
    float s = q * softplus_f(w_sig[co]);
    if (!(mu > 0.f)) { mu = 0.f; s = 0.f; }
    size_t oidx = (size_t)pix * Cout + co;
    mu_out[oidx] = mu;
    s_out[oidx]  = s;
}

// Fused conv_inter: each thread computes 4 output channels + redundant q.
// mu = conv3x3(mu_in, w_mu); s = q*softplus(w_sig) + conv3x3(s_in, w_mu^2)
// where q = patch-sum over (mu^2 + s). Optional relu.
// blockDim.x = Cout/4, blockDim.y = pixels per block.
__global__ void conv_inter_fused(const float* __restrict__ mu_in,
                                 const float* __restrict__ s_in,
                                 const float* __restrict__ w_mu,
                                 const float* __restrict__ w_sig,
                                 float* __restrict__ mu_out,
                                 float* __restrict__ s_out,
                                 int B, int Hin, int Win, int Cin,
                                 int Hout, int Wout, int Cout,
                                 int pad, int do_relu)
{
    int cog = threadIdx.x * 4;
    int pix = blockIdx.x * blockDim.y + threadIdx.y;
    int total = B * Hout * Wout;
    if (pix >= total) return;
    int b = pix / (Hout * Wout);
    int rem = pix % (Hout * Wout);
    int h = rem / Wout, w = rem % Wout;

    float4 mu4 = {0.f, 0.f, 0.f, 0.f};
    float4 sa4 = {0.f, 0.f, 0.f, 0.f};
    float q = 0.f;

    for (int kh = 0; kh < 3; kh++) {
        int ih = h + kh - pad;
        if (ih < 0 || ih >= Hin) continue;
        for (int kw = 0; kw < 3; kw++) {
            int iw = w + kw - pad;
            if (iw < 0 || iw >= Win) continue;
            size_t base = ((size_t)(b * Hin + ih) * Win + iw) * Cin;
            const float* mp = mu_in + base;
            const float* sp = s_in + base;
            const float* wp = w_mu + (size_t)((kh * 3 + kw) * Cin) * Cout + cog;
            for (int ci = 0; ci < Cin; ci += 4) {
                float4 m4 = *(const float4*)(mp + ci);
                float4 s4 = *(const float4*)(sp + ci);
                const float* wb = wp + (size_t)ci * Cout;
                float4 w0 = *(const float4*)(wb);
                float4 w1 = *(const float4*)(wb + Cout);
                float4 w2 = *(const float4*)(wb + 2 * Cout);
                float4 w3 = *(const float4*)(wb + 3 * Cout);
                q += m4.x * m4.x + s4.x + m4.y * m4.y + s4.y
                   + m4.z * m4.z + s4.z + m4.w * m4.w + s4.w;
                mu4.x += m4.x * w0.x + m4.y * w1.x + m4.z * w2.x + m4.w * w3.x;
                mu4.y += m4.x * w0.y + m4.y * w1.y + m4.z * w2.y + m4.w * w3.y;
                mu4.z += m4.x * w0.z + m4.y * w1.z + m4.z * w2.z + m4.w * w3.z;
                mu4.w += m4.x * w0.w + m4.y * w1.w + m4.z * w2.w + m4.w * w3.w;
                sa4.x += s4.x * (w0.x * w0.x) + s4.y * (w1.x * w1.x)
                       + s4.z * (w2.x * w2.x) + s4.w * (w3.x * w3.x);
                sa4.y += s4.x * (w0.y * w0.y) + s4.y * (w1.y * w1.y)
                       + s4.z * (w2.y * w2.y) + s4.w * (w3.y * w3.y);
                sa4.z += s4.x * (w0.z * w0.z) + s4.y * (w1.z * w1.z)
                       + s4.z * (w2.z * w2.z) + s4.w * (w3.z * w3.z);
                sa4.w += s4.x * (w0.w * w0.w) + s4.y * (w1.w * w1.w)
                       + s4.z * (w2.w * w2.w) + s4.w * (w3.w * w3.w);
            }
        }
    }
    float4 so;
    so.x = q * softplus_f(w_sig[cog + 0]) + sa4.x;
    so.y = q * softplus_f(w_sig[cog + 1]) + sa4.y;
    so.z = q * softplus_f(w_sig[cog + 2]) + sa4.z;
    so.w = q * softplus_f(w_sig[cog + 3]) + sa4.w;
    if (do_relu) {
        if (!(mu4.x > 0.f)) { mu4.x = 0.f; so.x = 0.f; }
        if (!(mu4.y > 0.f)) { mu4.y = 0.f; so.y = 0.f; }
        if (!(mu4.z > 0.f)) { mu4.z = 0.f; so.z = 0.f; }
        if (!(mu4.w > 0.f)) { mu4.w = 0.f; so.w = 0.f; }
    }
    size_t oidx = (size_t)pix * Cout + cog;
    *(float4*)(mu_out + oidx) = mu4;
    *(float4*)(s_out + oidx)  = so;
}

// conv_inter fused with zero-insertion unpool of the input.
// Input: pooled tensor [B,Hin,Win,Cin]. Logical input = unpool(in) [2Hin+1, 2Win+1],
// then VALID 3x3 conv -> [2Hin-1, 2Win-1]. Only taps with both coords odd are
// nonzero: 1, 2, or 4 live taps depending on output parity.
__global__ void conv_unpool_fused(const float* __restrict__ mu_in,
                                  const float* __restrict__ s_in,
                                  const float* __restrict__ w_mu,
                                  const float* __restrict__ w_sig,
                                  float* __restrict__ mu_out,
                                  float* __restrict__ s_out,
                                  int B, int Hin, int Win, int Cin,
                                  int Hout, int Wout, int Cout,
                                  int do_relu)
{
    int cog = threadIdx.x * 4;
    int pix = blockIdx.x * blockDim.y + threadIdx.y;
    int total = B * Hout * Wout;
    if (pix >= total) return;
    int b = pix / (Hout * Wout);
    int rem = pix % (Hout * Wout);
    int ho = rem / Wout, wo = rem % Wout;

    int khs[2], ihs[2], nkh;
    if (ho & 1) { nkh = 2; khs[0] = 0; ihs[0] = (ho - 1) >> 1; khs[1] = 2; ihs[1] = (ho + 1) >> 1; }
    else        { nkh = 1; khs[0] = 1; ihs[0] = ho >> 1; }
    int kws[2], iws[2], nkw;
    if (wo & 1) { nkw = 2; kws[0] = 0; iws[0] = (wo - 1) >> 1; kws[1] = 2; iws[1] = (wo + 1) >> 1; }
    else        { nkw = 1; kws[0] = 1; iws[0] = wo >> 1; }

    float4 mu4 = {0.f, 0.f, 0.f, 0.f};
    float4 sa4 = {0.f, 0.f, 0.f, 0.f};
    float q = 0.f;

    for (int a = 0; a < nkh; a++) {
        for (int c = 0; c < nkw; c++) {
            size_t base = ((size_t)(b * Hin + ihs[a]) * Win + iws[c]) * Cin;
            const float* mp = mu_in + base;
            const float* sp = s_in + base;
            const float* wp = w_mu + (size_t)((khs[a] * 3 + kws[c]) * Cin) * Cout + cog;
            for (int ci = 0; ci < Cin; ci += 4) {
                float4 m4 = *(const float4*)(mp + ci);
                float4 s4 = *(const float4*)(sp + ci);
                const float* wb = wp + (size_t)ci * Cout;
                float4 w0 = *(const float4*)(wb);
                float4 w1 = *(const float4*)(wb + Cout);
                float4 w2 = *(const float4*)(wb + 2 * Cout);
                float4 w3 = *(const float4*)(wb + 3 * Cout);
                q += m4.x * m4.x + s4.x + m4.y * m4.y + s4.y
                   + m4.z * m4.z + s4.z + m4.w * m4.w + s4.w;
                mu4.x += m4.x * w0.x + m4.y * w1.x + m4.z * w2.x + m4.w * w3.x;
                mu4.y += m4.x * w0.y + m4.y * w1.y + m4.z * w2.y + m4.w * w3.y;
                mu4.z += m4.x * w0.z + m4.y * w1.z + m4.z * w2.z + m4.w * w3.z;
                mu4.w += m4.x * w0.w + m4.y * w1.w + m4.z * w2.w + m4.w * w3.w;
                sa4.x += s4.x * (w0.x * w0.x) + s4.y * (w1.x * w1.x)
                       + s4.z * (w2.x * w2.x) + s4.w * (w3.x * w3.x);
                sa4.y += s4.x * (w0.y * w0.y) + s4.y * (w1.y * w1.y)
                       + s4.z * (w2.y * w2.y) + s4.w * (w3.y * w3.y);
                sa4.z += s4.x * (w0.z * w0.z) + s4.y * (w1.z * w1.z)
                       + s4.z * (w2.z * w2.z) + s4.w * (w3.z * w3.z);
                sa4.w += s4.x * (w0.w * w0.w) + s4.y * (w1.w * w1.w)
                       + s4.z * (w2.w * w2.w) + s4.w * (w3.w * w3.w);
            }
        }
    }
    float4 so;
    so.x = q * softplus_f(w_sig[cog + 0]) + sa4.x;
    so.y = q * softplus_f(w_sig[cog + 1]) + sa4.y;
    so.z = q * softplus_f(w_sig[cog + 2]) + sa4.z;
    so.w = q * softplus_f(w_sig[cog + 3]) + sa4.w;
    if (do_relu) {
        if (!(mu4.x > 0.f)) { mu4.x = 0.f; so.x = 0.f; }
        if (!(mu4.y > 0.f)) { mu4.y = 0.f; so.y = 0.f; }
        if (!(mu4.z > 0.f)) { mu4.z = 0.f; so.z = 0.f; }
        if (!(mu4.w > 0.f)) { mu4.w = 0.f; so.w = 0.f; }
    }
    size_t oidx = (size_t)pix * Cout + cog;
    *(float4*)(mu_out + oidx) = mu4;
    *(float4*)(s_out + oidx)  = so;
}

// 2x2/stride-2 argmax pool; gather s at argmax.
__global__ void pool_kernel(const float* __restrict__ mu_in,
                            const float* __restrict__ s_in,
                            float* __restrict__ mu_out,
                            float* __restrict__ s_out,
                            int B, int H, int W, int C)
{
    int Ho = H / 2, Wo = W / 2;
    size_t total = (size_t)B * Ho * Wo * C;
    size_t idx = (size_t)blockIdx.x * blockDim.x + threadIdx.x;
    if (idx >= total) return;
    int c = idx % C;
    size_t t = idx / C;
    int w = t % Wo; t /= Wo;
    int h = t % Ho;
    int b = t / Ho;
    size_t i0 = ((size_t)(b * H + 2 * h) * W + 2 * w) * C + c;
    size_t rowStride = (size_t)W * C;
    float m00 = mu_in[i0], m01 = mu_in[i0 + C];
    float m10 = mu_in[i0 + rowStride], m11 = mu_in[i0 + rowStride + C];
    int best = 0; float bm = m00;
    if (m01 > bm) { bm = m01; best = 1; }
    if (m10 > bm) { bm = m10; best = 2; }
    if (m11 > bm) { bm = m11; best = 3; }
    size_t off = (size_t)(best >> 1) * rowStride + (size_t)(best & 1) * C;
    mu_out[idx] = bm;
    s_out[idx]  = s_in[i0 + off];
}

// channel concat: out[...,0:Cd)=dec, out[...,Cd:Cd+Ce)=enc[b, h+dh, w+dw, :]
__global__ void concat_kernel(const float* __restrict__ dec,
                              const float* __restrict__ enc,
                              float* __restrict__ out,
                              int B, int H, int W, int Cd, int Ce,
                              int Henc, int Wenc, int dh, int dw)
{
    int C = Cd + Ce;
    size_t total = (size_t)B * H * W * C;
    size_t idx = (size_t)blockIdx.x * blockDim.x + threadIdx.x;
    if (idx >= total) return;
    int c = idx % C;
    size_t t = idx / C;
    int w = t % W; t /= W;
    int h = t % H;
    int b = t / H;
    float v;
    if (c < Cd)
        v = dec[((size_t)(b * H + h) * W + w) * Cd + c];
    else
        v = enc[((size_t)(b * Henc + h + dh) * Wenc + (w + dw)) * Ce + (c - Cd)];
    out[idx] = v;
}

// 1x1 conv_inter (Cin -> 2, no relu) fused with C=2 softmax density propagation.
__global__ void final_kernel(const float* __restrict__ mu_in,
                             const float* __restrict__ s_in,
                             const float* __restrict__ w_mu,
                             const float* __restrict__ w_sig,
                             float* __restrict__ out,
                             int B, int H, int W, int Cin)
{
    int pix = blockIdx.x * blockDim.x + threadIdx.x;
    int total = B * H * W;
    if (pix >= total) return;
    const float* mp = mu_in + (size_t)pix * Cin;
    const float* sp = s_in + (size_t)pix * Cin;
    float mu0 = 0.f, mu1 = 0.f, s0a = 0.f, s1a = 0.f, q = 0.f;
    for (int ci = 0; ci < Cin; ci++) {
        float m = mp[ci], s = sp[ci];
        float w0 = w_mu[ci * 2], w1 = w_mu[ci * 2 + 1];
        mu0 += m * w0; mu1 += m * w1;
        s0a += s * (w0 * w0); s1a += s * (w1 * w1);
        q += m * m + s;
    }
    float s0 = q * softplus_f(w_sig[0]) + s0a;
    float s1 = q * softplus_f(w_sig[1]) + s1a;
    float mx = fmaxf(mu0, mu1);
    float e0 = expf(mu0 - mx), e1 = expf(mu1 - mx);
    float inv = 1.f / (e0 + e1);
    float p0 = e0 * inv, p1 = e1 * inv;
    float g00 = p0 - p0 * p0, g01 = -p0 * p1;
    float g10 = -p1 * p0,     g11 = p1 - p1 * p1;
    float so0 = g00 * g00 * s0 + g01 * g01 * s1;
    float so1 = g10 * g10 * s0 + g11 * g11 * s1;
    out[(size_t)pix * 2]     = p0;
    out[(size_t)pix * 2 + 1] = p1;
    size_t off = (size_t)total * 2;
    out[off + (size_t)pix * 2]     = so0;
    out[off + (size_t)pix * 2 + 1] = so1;
}

// ---------------------------------------------------------------------------

extern "C" void kernel_launch(void* const* d_in, const int* in_sizes, int n_in,
                              void* d_out, int out_size, void* d_ws, size_t ws_size,
                              hipStream_t stream)
{
    const float* x = (const float*)d_in[0];
    enum { E1A, E1B, E2A, E2B, BA, BB, D2U, D2A, D2B, D1U, D1A, D1B, FIN, NW };
    const float* wmu[NW];
    const float* wsig[NW];
    for (int i = 0; i < NW; i++) {
        wmu[i]  = (const float*)d_in[1 + 2 * i];
        wsig[i] = (const float*)d_in[2 + 2 * i];
    }

    const int B = 4;
    const size_t BUFSZ = 8258048;             // max tensor: 4*127*127*128 (not all used now)
    float* ws = (float*)d_ws;
    float* Amu = ws;
    float* As  = ws + BUFSZ;
    float* Bmu = ws + 2 * BUFSZ;
    float* Bs  = ws + 3 * BUFSZ;
    float* E1mu = ws + 4 * BUFSZ;             // 4*128*128*64 = 4194304
    float* E1s  = E1mu + 4194304;
    float* E2mu = E1s + 4194304;              // 4*64*64*128 = 2097152
    float* E2s  = E2mu + 2097152;

    auto launch_conv = [&](const float* mi, const float* si,
                           int hi, int wi, int ci,
                           int ho, int wo, int co,
                           int pad, int relu, int widx,
                           float* mo, float* so) {
        int totalPix = B * ho * wo;
        int ty = 256 / (co / 4);
        dim3 blk(co / 4, ty);
        dim3 grd((totalPix + ty - 1) / ty);
        conv_inter_fused<<<grd, blk, 0, stream>>>(
            mi, si, wmu[widx], wsig[widx], mo, so,
            B, hi, wi, ci, ho, wo, co, pad, relu);
    };

    auto launch_conv_unpool = [&](const float* mi, const float* si,
                                  int hi, int wi, int ci,
                                  int ho, int wo, int co,
                                  int relu, int widx,
                                  float* mo, float* so) {
        int totalPix = B * ho * wo;
        int ty = 256 / (co / 4);
        dim3 blk(co / 4, ty);
        dim3 grd((totalPix + ty - 1) / ty);
        conv_unpool_fused<<<grd, blk, 0, stream>>>(
            mi, si, wmu[widx], wsig[widx], mo, so,
            B, hi, wi, ci, ho, wo, co, relu);
    };

    // ---- encoder level 1 ----
    {
        int totalPix = B * 128 * 128;
        conv_input_relu_kernel<<<dim3((totalPix + 3) / 4), dim3(64, 4), 0, stream>>>(
            x, wmu[E1A], wsig[E1A], Amu, As, B, 128, 128, 3, 64);
    }
    launch_conv(Amu, As, 128, 128, 64, 128, 128, 64, 1, 1, E1B, E1mu, E1s);
    {
        size_t total = (size_t)B * 64 * 64 * 64;
        pool_kernel<<<dim3((total + 255) / 256), dim3(256), 0, stream>>>(
            E1mu, E1s, Amu, As, B, 128, 128, 64);
    }
    // ---- encoder level 2 ----
    launch_conv(Amu, As, 64, 64, 64, 64, 64, 128, 1, 1, E2A, Bmu, Bs);
    launch_conv(Bmu, Bs, 64, 64, 128, 64, 64, 128, 1, 1, E2B, E2mu, E2s);
    {
        size_t total = (size_t)B * 32 * 32 * 128;
        pool_kernel<<<dim3((total + 255) / 256), dim3(256), 0, stream>>>(
            E2mu, E2s, Amu, As, B, 64, 64, 128);
    }
    // ---- bottleneck ----
    launch_conv(Amu, As, 32, 32, 128, 32, 32, 256, 1, 1, BA, Bmu, Bs);
    launch_conv(Bmu, Bs, 32, 32, 256, 32, 32, 256, 1, 1, BB, Amu, As);
    // ---- decoder level 2 (unpool fused into conv) ----
    launch_conv_unpool(Amu, As, 32, 32, 256, 63, 63, 128, 1, D2U, Bmu, Bs);
    {
        size_t total = (size_t)B * 63 * 63 * 256;
        concat_kernel<<<dim3((total + 255) / 256), dim3(256), 0, stream>>>(
            Bmu, E2mu, Amu, B, 63, 63, 128, 128, 64, 64, 0, 0);
        concat_kernel<<<dim3((total + 255) / 256), dim3(256), 0, stream>>>(
            Bs, E2s, As, B, 63, 63, 128, 128, 64, 64, 0, 0);
    }
    launch_conv(Amu, As, 63, 63, 256, 63, 63, 128, 1, 1, D2A, Bmu, Bs);
    launch_conv(Bmu, Bs, 63, 63, 128, 63, 63, 128, 1, 1, D2B, Amu, As);
    // ---- decoder level 1 (unpool fused into conv) ----
    launch_conv_unpool(Amu, As, 63, 63, 128, 125, 125, 64, 1, D1U, Bmu, Bs);
    {
        size_t total = (size_t)B * 125 * 125 * 128;
        concat_kernel<<<dim3((total + 255) / 256), dim3(256), 0, stream>>>(
            Bmu, E1mu, Amu, B, 125, 125, 64, 64, 128, 128, 1, 1);
        concat_kernel<<<dim3((total + 255) / 256), dim3(256), 0, stream>>>(
            Bs, E1s, As, B, 125, 125, 64, 64, 128, 128, 1, 1);
    }
    launch_conv(Amu, As, 125, 125, 128, 125, 125, 64, 1, 1, D1A, Bmu, Bs);
    launch_conv(Bmu, Bs, 125, 125, 64, 125, 125, 64, 1, 1, D1B, Amu, As);
    // ---- final 1x1 + softmax prop ----
    {
        int totalPix = B * 125 * 125;
        final_kernel<<<dim3((totalPix + 255) / 256), dim3(256), 0, stream>>>(
            Amu, As, wmu[FIN], wsig[FIN], (float*)d_out, B, 125, 125, 64);
    }
}

// Round 3
// 4791.177 us; speedup vs baseline: 3.6277x; 1.0065x over previous
//
#include <hip/hip_runtime.h>
#include <math.h>

// ---------------------------------------------------------------------------
// Variance-propagating UNet (density prop), fp32, NHWC.
// Round 2: 4-pixel-per-thread register blocking in conv (weights + w^2 shared
// across pixels), concat fused into d2a/d1a convs (two-source ci loop),
// float4 final kernel.
// ---------------------------------------------------------------------------

__device__ __forceinline__ float softplus_f(float x) { return log1pf(expf(x)); }

// First layer: mu = conv3x3(pad(x), w_mu); s = (patch-sum of x^2) * softplus(w_sig[co]); relu.
__global__ void conv_input_relu_kernel(const float* __restrict__ x,
                                       const float* __restrict__ w_mu,
                                       const float* __restrict__ w_sig,
                                       float* __restrict__ mu_out,
                                       float* __restrict__ s_out,
                                       int B, int H, int W, int Cin, int Cout)
{
    int co  = threadIdx.x;
    int pix = blockIdx.x * blockDim.y + threadIdx.y;
    int total = B * H * W;
    if (pix >= total) return;
    int b = pix / (H * W);
    int rem = pix % (H * W);
    int h = rem / W, w = rem % W;

    float mu = 0.f, q = 0.f;
    for (int kh = 0; kh < 3; kh++) {
        int ih = h + kh - 1;
        if (ih < 0 || ih >= H) continue;
        for (int kw = 0; kw < 3; kw++) {
            int iw = w + kw - 1;
            if (iw < 0 || iw >= W) continue;
            const float* xp = x + ((size_t)(b * H + ih) * W + iw) * Cin;
            const float* wp = w_mu + (size_t)((kh * 3 + kw) * Cin) * Cout + co;
            for (int ci = 0; ci < Cin; ci++) {
                float xv = xp[ci];
                mu += xv * wp[(size_t)ci * Cout];
                q  += xv * xv;
            }
        }
    }
    float s = q * softplus_f(w_sig[co]);
    if (!(mu > 0.f)) { mu = 0.f; s = 0.f; }
    size_t oidx = (size_t)pix * Cout + co;
    mu_out[oidx] = mu;
    s_out[oidx]  = s;
}

// Main conv kernel: 4 output channels x 4 consecutive W-pixels per thread.
// Optional second input source (fused skip-concat): logical input channel
// range [Cin1, Cin1+Cin2) comes from (mu2,s2) at spatial offset (dh,dw) in a
// [B,H2,W2,Cin2] tensor. Bounds (padding) are those of the logical input
// [B,Hin,Win,:] for BOTH sources.
__global__ void __launch_bounds__(256)
conv4_kernel(const float* __restrict__ mu1, const float* __restrict__ s1,
             const float* __restrict__ mu2, const float* __restrict__ s2,
             const float* __restrict__ w_mu, const float* __restrict__ w_sig,
             float* __restrict__ mu_out, float* __restrict__ s_out,
             int B, int Hin, int Win, int Cin1, int Cin2,
             int H2, int W2, int dh, int dw,
             int Hout, int Wout, int Cout, int pad, int do_relu)
{
    const int cog = threadIdx.x * 4;
    const int qpr = (Wout + 3) >> 2;
    int quad = blockIdx.x * blockDim.y + threadIdx.y;
    int totalQ = B * Hout * qpr;
    if (quad >= totalQ) return;
    int b = quad / (Hout * qpr);
    int rem = quad - b * (Hout * qpr);
    int h = rem / qpr;
    int wq = (rem - h * qpr) << 2;
    const int Cin = Cin1 + Cin2;

    float4 amu[4], asa[4];
    float q[4];
#pragma unroll
    for (int p = 0; p < 4; p++) {
        amu[p] = make_float4(0.f, 0.f, 0.f, 0.f);
        asa[p] = make_float4(0.f, 0.f, 0.f, 0.f);
        q[p] = 0.f;
    }

    for (int kh = 0; kh < 3; kh++) {
        int ih = h + kh - pad;
        if (ih < 0 || ih >= Hin) continue;
        for (int kw = 0; kw < 3; kw++) {
            int iwb = wq + kw - pad;
            bool v[4];
#pragma unroll
            for (int p = 0; p < 4; p++) {
                int iw = iwb + p;
                v[p] = ((unsigned)iw < (unsigned)Win) && ((wq + p) < Wout);
            }
            const float* __restrict__ wp =
                w_mu + (size_t)((kh * 3 + kw) * Cin) * Cout + cog;
            // ---- source 1 ----
            {
                const size_t rowb = ((size_t)(b * Hin + ih) * Win) * (size_t)Cin1;
                for (int ci = 0; ci < Cin1; ci += 4) {
                    const float* wb = wp + (size_t)ci * Cout;
                    float4 w0 = *(const float4*)(wb);
                    float4 w1 = *(const float4*)(wb + Cout);
                    float4 w2 = *(const float4*)(wb + 2 * Cout);
                    float4 w3 = *(const float4*)(wb + 3 * Cout);
                    float4 ww0 = make_float4(w0.x*w0.x, w0.y*w0.y, w0.z*w0.z, w0.w*w0.w);
                    float4 ww1 = make_float4(w1.x*w1.x, w1.y*w1.y, w1.z*w1.z, w1.w*w1.w);
                    float4 ww2 = make_float4(w2.x*w2.x, w2.y*w2.y, w2.z*w2.z, w2.w*w2.w);
                    float4 ww3 = make_float4(w3.x*w3.x, w3.y*w3.y, w3.z*w3.z, w3.w*w3.w);
#pragma unroll
                    for (int p = 0; p < 4; p++) {
                        if (!v[p]) continue;
                        size_t base = rowb + (size_t)(iwb + p) * Cin1 + ci;
                        float4 m4 = *(const float4*)(mu1 + base);
                        float4 s4 = *(const float4*)(s1 + base);
                        q[p] += m4.x*m4.x + s4.x + m4.y*m4.y + s4.y
                              + m4.z*m4.z + s4.z + m4.w*m4.w + s4.w;
                        amu[p].x += m4.x*w0.x + m4.y*w1.x + m4.z*w2.x + m4.w*w3.x;
                        amu[p].y += m4.x*w0.y + m4.y*w1.y + m4.z*w2.y + m4.w*w3.y;
                        amu[p].z += m4.x*w0.z + m4.y*w1.z + m4.z*w2.z + m4.w*w3.z;
                        amu[p].w += m4.x*w0.w + m4.y*w1.w + m4.z*w2.w + m4.w*w3.w;
                        asa[p].x += s4.x*ww0.x + s4.y*ww1.x + s4.z*ww2.x + s4.w*ww3.x;
                        asa[p].y += s4.x*ww0.y + s4.y*ww1.y + s4.z*ww2.y + s4.w*ww3.y;
                        asa[p].z += s4.x*ww0.z + s4.y*ww1.z + s4.z*ww2.z + s4.w*ww3.z;
                        asa[p].w += s4.x*ww0.w + s4.y*ww1.w + s4.z*ww2.w + s4.w*ww3.w;
                    }
                }
            }
            // ---- source 2 (fused skip concat) ----
            if (Cin2 > 0) {
                const size_t rowb2 = ((size_t)(b * H2 + ih + dh) * W2) * (size_t)Cin2;
                const float* __restrict__ wp2 = wp + (size_t)Cin1 * Cout;
                for (int ci = 0; ci < Cin2; ci += 4) {
                    const float* wb = wp2 + (size_t)ci * Cout;
                    float4 w0 = *(const float4*)(wb);
                    float4 w1 = *(const float4*)(wb + Cout);
                    float4 w2 = *(const float4*)(wb + 2 * Cout);
                    float4 w3 = *(const float4*)(wb + 3 * Cout);
                    float4 ww0 = make_float4(w0.x*w0.x, w0.y*w0.y, w0.z*w0.z, w0.w*w0.w);
                    float4 ww1 = make_float4(w1.x*w1.x, w1.y*w1.y, w1.z*w1.z, w1.w*w1.w);
                    float4 ww2 = make_float4(w2.x*w2.x, w2.y*w2.y, w2.z*w2.z, w2.w*w2.w);
                    float4 ww3 = make_float4(w3.x*w3.x, w3.y*w3.y, w3.z*w3.z, w3.w*w3.w);
#pragma unroll
                    for (int p = 0; p < 4; p++) {
                        if (!v[p]) continue;
                        size_t base = rowb2 + (size_t)(iwb + p + dw) * Cin2 + ci;
                        float4 m4 = *(const float4*)(mu2 + base);
                        float4 s4 = *(const float4*)(s2 + base);
                        q[p] += m4.x*m4.x + s4.x + m4.y*m4.y + s4.y
                              + m4.z*m4.z + s4.z + m4.w*m4.w + s4.w;
                        amu[p].x += m4.x*w0.x + m4.y*w1.x + m4.z*w2.x + m4.w*w3.x;
                        amu[p].y += m4.x*w0.y + m4.y*w1.y + m4.z*w2.y + m4.w*w3.y;
                        amu[p].z += m4.x*w0.z + m4.y*w1.z + m4.z*w2.z + m4.w*w3.z;
                        amu[p].w += m4.x*w0.w + m4.y*w1.w + m4.z*w2.w + m4.w*w3.w;
                        asa[p].x += s4.x*ww0.x + s4.y*ww1.x + s4.z*ww2.x + s4.w*ww3.x;
                        asa[p].y += s4.x*ww0.y + s4.y*ww1.y + s4.z*ww2.y + s4.w*ww3.y;
                        asa[p].z += s4.x*ww0.z + s4.y*ww1.z + s4.z*ww2.z + s4.w*ww3.z;
                        asa[p].w += s4.x*ww0.w + s4.y*ww1.w + s4.z*ww2.w + s4.w*ww3.w;
                    }
                }
            }
        }
    }

    float4 sg = *(const float4*)(w_sig + cog);
    float sp0 = softplus_f(sg.x), sp1 = softplus_f(sg.y);
    float sp2 = softplus_f(sg.z), sp3 = softplus_f(sg.w);
#pragma unroll
    for (int p = 0; p < 4; p++) {
        int wo = wq + p;
        if (wo >= Wout) continue;
        float4 m = amu[p];
        float4 s;
        s.x = q[p] * sp0 + asa[p].x;
        s.y = q[p] * sp1 + asa[p].y;
        s.z = q[p] * sp2 + asa[p].z;
        s.w = q[p] * sp3 + asa[p].w;
        if (do_relu) {
            if (!(m.x > 0.f)) { m.x = 0.f; s.x = 0.f; }
            if (!(m.y > 0.f)) { m.y = 0.f; s.y = 0.f; }
            if (!(m.z > 0.f)) { m.z = 0.f; s.z = 0.f; }
            if (!(m.w > 0.f)) { m.w = 0.f; s.w = 0.f; }
        }
        size_t pix = (size_t)(b * Hout + h) * Wout + wo;
        *(float4*)(mu_out + pix * Cout + cog) = m;
        *(float4*)(s_out  + pix * Cout + cog) = s;
    }
}

// conv_inter fused with zero-insertion unpool of the input (1/2/4 live taps).
__global__ void conv_unpool_fused(const float* __restrict__ mu_in,
                                  const float* __restrict__ s_in,
                                  const float* __restrict__ w_mu,
                                  const float* __restrict__ w_sig,
                                  float* __restrict__ mu_out,
                                  float* __restrict__ s_out,
                                  int B, int Hin, int Win, int Cin,
                                  int Hout, int Wout, int Cout,
                                  int do_relu)
{
    int cog = threadIdx.x * 4;
    int pix = blockIdx.x * blockDim.y + threadIdx.y;
    int total = B * Hout * Wout;
    if (pix >= total) return;
    int b = pix / (Hout * Wout);
    int rem = pix % (Hout * Wout);
    int ho = rem / Wout, wo = rem % Wout;

    int khs[2], ihs[2], nkh;
    if (ho & 1) { nkh = 2; khs[0] = 0; ihs[0] = (ho - 1) >> 1; khs[1] = 2; ihs[1] = (ho + 1) >> 1; }
    else        { nkh = 1; khs[0] = 1; ihs[0] = ho >> 1; }
    int kws[2], iws[2], nkw;
    if (wo & 1) { nkw = 2; kws[0] = 0; iws[0] = (wo - 1) >> 1; kws[1] = 2; iws[1] = (wo + 1) >> 1; }
    else        { nkw = 1; kws[0] = 1; iws[0] = wo >> 1; }

    float4 mu4 = {0.f, 0.f, 0.f, 0.f};
    float4 sa4 = {0.f, 0.f, 0.f, 0.f};
    float q = 0.f;

    for (int a = 0; a < nkh; a++) {
        for (int c = 0; c < nkw; c++) {
            size_t base = ((size_t)(b * Hin + ihs[a]) * Win + iws[c]) * Cin;
            const float* mp = mu_in + base;
            const float* sp = s_in + base;
            const float* wp = w_mu + (size_t)((khs[a] * 3 + kws[c]) * Cin) * Cout + cog;
            for (int ci = 0; ci < Cin; ci += 4) {
                float4 m4 = *(const float4*)(mp + ci);
                float4 s4 = *(const float4*)(sp + ci);
                const float* wb = wp + (size_t)ci * Cout;
                float4 w0 = *(const float4*)(wb);
                float4 w1 = *(const float4*)(wb + Cout);
                float4 w2 = *(const float4*)(wb + 2 * Cout);
                float4 w3 = *(const float4*)(wb + 3 * Cout);
                q += m4.x * m4.x + s4.x + m4.y * m4.y + s4.y
                   + m4.z * m4.z + s4.z + m4.w * m4.w + s4.w;
                mu4.x += m4.x * w0.x + m4.y * w1.x + m4.z * w2.x + m4.w * w3.x;
                mu4.y += m4.x * w0.y + m4.y * w1.y + m4.z * w2.y + m4.w * w3.y;
                mu4.z += m4.x * w0.z + m4.y * w1.z + m4.z * w2.z + m4.w * w3.z;
                mu4.w += m4.x * w0.w + m4.y * w1.w + m4.z * w2.w + m4.w * w3.w;
                sa4.x += s4.x * (w0.x * w0.x) + s4.y * (w1.x * w1.x)
                       + s4.z * (w2.x * w2.x) + s4.w * (w3.x * w3.x);
                sa4.y += s4.x * (w0.y * w0.y) + s4.y * (w1.y * w1.y)
                       + s4.z * (w2.y * w2.y) + s4.w * (w3.y * w3.y);
                sa4.z += s4.x * (w0.z * w0.z) + s4.y * (w1.z * w1.z)
                       + s4.z * (w2.z * w2.z) + s4.w * (w3.z * w3.z);
                sa4.w += s4.x * (w0.w * w0.w) + s4.y * (w1.w * w1.w)
                       + s4.z * (w2.w * w2.w) + s4.w * (w3.w * w3.w);
            }
        }
    }
    float4 so;
    so.x = q * softplus_f(w_sig[cog + 0]) + sa4.x;
    so.y = q * softplus_f(w_sig[cog + 1]) + sa4.y;
    so.z = q * softplus_f(w_sig[cog + 2]) + sa4.z;
    so.w = q * softplus_f(w_sig[cog + 3]) + sa4.w;
    if (do_relu) {
        if (!(mu4.x > 0.f)) { mu4.x = 0.f; so.x = 0.f; }
        if (!(mu4.y > 0.f)) { mu4.y = 0.f; so.y = 0.f; }
        if (!(mu4.z > 0.f)) { mu4.z = 0.f; so.z = 0.f; }
        if (!(mu4.w > 0.f)) { mu4.w = 0.f; so.w = 0.f; }
    }
    size_t oidx = (size_t)pix * Cout + cog;
    *(float4*)(mu_out + oidx) = mu4;
    *(float4*)(s_out + oidx)  = so;
}

// 2x2/stride-2 argmax pool; gather s at argmax.
__global__ void pool_kernel(const float* __restrict__ mu_in,
                            const float* __restrict__ s_in,
                            float* __restrict__ mu_out,
                            float* __restrict__ s_out,
                            int B, int H, int W, int C)
{
    int Ho = H / 2, Wo = W / 2;
    size_t total = (size_t)B * Ho * Wo * C;
    size_t idx = (size_t)blockIdx.x * blockDim.x + threadIdx.x;
    if (idx >= total) return;
    int c = idx % C;
    size_t t = idx / C;
    int w = t % Wo; t /= Wo;
    int h = t % Ho;
    int b = t / Ho;
    size_t i0 = ((size_t)(b * H + 2 * h) * W + 2 * w) * C + c;
    size_t rowStride = (size_t)W * C;
    float m00 = mu_in[i0], m01 = mu_in[i0 + C];
    float m10 = mu_in[i0 + rowStride], m11 = mu_in[i0 + rowStride + C];
    int best = 0; float bm = m00;
    if (m01 > bm) { bm = m01; best = 1; }
    if (m10 > bm) { bm = m10; best = 2; }
    if (m11 > bm) { bm = m11; best = 3; }
    size_t off = (size_t)(best >> 1) * rowStride + (size_t)(best & 1) * C;
    mu_out[idx] = bm;
    s_out[idx]  = s_in[i0 + off];
}

// 1x1 conv_inter (Cin -> 2, no relu) fused with C=2 softmax density propagation.
__global__ void final_kernel(const float* __restrict__ mu_in,
                             const float* __restrict__ s_in,
                             const float* __restrict__ w_mu,
                             const float* __restrict__ w_sig,
                             float* __restrict__ out,
                             int B, int H, int W, int Cin)
{
    int pix = blockIdx.x * blockDim.x + threadIdx.x;
    int total = B * H * W;
    if (pix >= total) return;
    const float* mp = mu_in + (size_t)pix * Cin;
    const float* sp = s_in + (size_t)pix * Cin;
    float mu0 = 0.f, mu1 = 0.f, s0a = 0.f, s1a = 0.f, q = 0.f;
    for (int ci = 0; ci < Cin; ci += 4) {
        float4 m = *(const float4*)(mp + ci);
        float4 s = *(const float4*)(sp + ci);
        float4 wa = *(const float4*)(w_mu + ci * 2);       // (w[ci][0], w[ci][1], w[ci+1][0], w[ci+1][1])
        float4 wb = *(const float4*)(w_mu + ci * 2 + 4);   // ci+2, ci+3
        mu0 += m.x * wa.x + m.y * wa.z + m.z * wb.x + m.w * wb.z;
        mu1 += m.x * wa.y + m.y * wa.w + m.z * wb.y + m.w * wb.w;
        s0a += s.x * (wa.x * wa.x) + s.y * (wa.z * wa.z) + s.z * (wb.x * wb.x) + s.w * (wb.z * wb.z);
        s1a += s.x * (wa.y * wa.y) + s.y * (wa.w * wa.w) + s.z * (wb.y * wb.y) + s.w * (wb.w * wb.w);
        q += m.x * m.x + s.x + m.y * m.y + s.y + m.z * m.z + s.z + m.w * m.w + s.w;
    }
    float s0 = q * softplus_f(w_sig[0]) + s0a;
    float s1 = q * softplus_f(w_sig[1]) + s1a;
    float mx = fmaxf(mu0, mu1);
    float e0 = expf(mu0 - mx), e1 = expf(mu1 - mx);
    float inv = 1.f / (e0 + e1);
    float p0 = e0 * inv, p1 = e1 * inv;
    float g00 = p0 - p0 * p0, g01 = -p0 * p1;
    float g10 = -p1 * p0,     g11 = p1 - p1 * p1;
    float so0 = g00 * g00 * s0 + g01 * g01 * s1;
    float so1 = g10 * g10 * s0 + g11 * g11 * s1;
    out[(size_t)pix * 2]     = p0;
    out[(size_t)pix * 2 + 1] = p1;
    size_t off = (size_t)total * 2;
    out[off + (size_t)pix * 2]     = so0;
    out[off + (size_t)pix * 2 + 1] = so1;
}

// ---------------------------------------------------------------------------

extern "C" void kernel_launch(void* const* d_in, const int* in_sizes, int n_in,
                              void* d_out, int out_size, void* d_ws, size_t ws_size,
                              hipStream_t stream)
{
    const float* x = (const float*)d_in[0];
    enum { E1A, E1B, E2A, E2B, BA, BB, D2U, D2A, D2B, D1U, D1A, D1B, FIN, NW };
    const float* wmu[NW];
    const float* wsig[NW];
    for (int i = 0; i < NW; i++) {
        wmu[i]  = (const float*)d_in[1 + 2 * i];
        wsig[i] = (const float*)d_in[2 + 2 * i];
    }

    const int B = 4;
    const size_t BUFSZ = 8258048;
    float* ws = (float*)d_ws;
    float* Amu = ws;
    float* As  = ws + BUFSZ;
    float* Bmu = ws + 2 * BUFSZ;
    float* Bs  = ws + 3 * BUFSZ;
    float* E1mu = ws + 4 * BUFSZ;             // 4*128*128*64 = 4194304
    float* E1s  = E1mu + 4194304;
    float* E2mu = E1s + 4194304;              // 4*64*64*128 = 2097152
    float* E2s  = E2mu + 2097152;

    // single-source conv
    auto launch_conv = [&](const float* mi, const float* si,
                           int hi, int wi, int ci,
                           int ho, int wo, int co,
                           int pad, int relu, int widx,
                           float* mo, float* so) {
        int qpr = (wo + 3) / 4;
        int totalQ = B * ho * qpr;
        int tx = co / 4;
        int ty = 256 / tx;
        dim3 blk(tx, ty);
        dim3 grd((totalQ + ty - 1) / ty);
        conv4_kernel<<<grd, blk, 0, stream>>>(
            mi, si, nullptr, nullptr, wmu[widx], wsig[widx], mo, so,
            B, hi, wi, ci, 0, 0, 0, 0, 0, ho, wo, co, pad, relu);
    };

    // two-source conv (fused skip concat)
    auto launch_conv2 = [&](const float* mi, const float* si, int ci1,
                            const float* me, const float* se, int ci2,
                            int h2, int w2, int dh, int dw,
                            int hi, int wi, int ho, int wo, int co,
                            int pad, int relu, int widx,
                            float* mo, float* so) {
        int qpr = (wo + 3) / 4;
        int totalQ = B * ho * qpr;
        int tx = co / 4;
        int ty = 256 / tx;
        dim3 blk(tx, ty);
        dim3 grd((totalQ + ty - 1) / ty);
        conv4_kernel<<<grd, blk, 0, stream>>>(
            mi, si, me, se, wmu[widx], wsig[widx], mo, so,
            B, hi, wi, ci1, ci2, h2, w2, dh, dw, ho, wo, co, pad, relu);
    };

    auto launch_conv_unpool = [&](const float* mi, const float* si,
                                  int hi, int wi, int ci,
                                  int ho, int wo, int co,
                                  int relu, int widx,
                                  float* mo, float* so) {
        int totalPix = B * ho * wo;
        int ty = 256 / (co / 4);
        dim3 blk(co / 4, ty);
        dim3 grd((totalPix + ty - 1) / ty);
        conv_unpool_fused<<<grd, blk, 0, stream>>>(
            mi, si, wmu[widx], wsig[widx], mo, so,
            B, hi, wi, ci, ho, wo, co, relu);
    };

    // ---- encoder level 1 ----
    {
        int totalPix = B * 128 * 128;
        conv_input_relu_kernel<<<dim3((totalPix + 3) / 4), dim3(64, 4), 0, stream>>>(
            x, wmu[E1A], wsig[E1A], Amu, As, B, 128, 128, 3, 64);
    }
    launch_conv(Amu, As, 128, 128, 64, 128, 128, 64, 1, 1, E1B, E1mu, E1s);
    {
        size_t total = (size_t)B * 64 * 64 * 64;
        pool_kernel<<<dim3((total + 255) / 256), dim3(256), 0, stream>>>(
            E1mu, E1s, Bmu, Bs, B, 128, 128, 64);
    }
    // ---- encoder level 2 ----
    launch_conv(Bmu, Bs, 64, 64, 64, 64, 64, 128, 1, 1, E2A, Amu, As);
    launch_conv(Amu, As, 64, 64, 128, 64, 64, 128, 1, 1, E2B, E2mu, E2s);
    {
        size_t total = (size_t)B * 32 * 32 * 128;
        pool_kernel<<<dim3((total + 255) / 256), dim3(256), 0, stream>>>(
            E2mu, E2s, Amu, As, B, 64, 64, 128);
    }
    // ---- bottleneck ----
    launch_conv(Amu, As, 32, 32, 128, 32, 32, 256, 1, 1, BA, Bmu, Bs);
    launch_conv(Bmu, Bs, 32, 32, 256, 32, 32, 256, 1, 1, BB, Amu, As);
    // ---- decoder level 2 ----
    launch_conv_unpool(Amu, As, 32, 32, 256, 63, 63, 128, 1, D2U, Bmu, Bs);
    // d2a: input = concat(d2u out [63x63x128], crop(E2) [offset 0,0]) -> 128 out
    launch_conv2(Bmu, Bs, 128, E2mu, E2s, 128, 64, 64, 0, 0,
                 63, 63, 63, 63, 128, 1, 1, D2A, Amu, As);
    launch_conv(Amu, As, 63, 63, 128, 63, 63, 128, 1, 1, D2B, Bmu, Bs);
    // ---- decoder level 1 ----
    launch_conv_unpool(Bmu, Bs, 63, 63, 128, 125, 125, 64, 1, D1U, Amu, As);
    // d1a: input = concat(d1u out [125x125x64], crop(E1) [offset 1,1]) -> 64 out
    launch_conv2(Amu, As, 64, E1mu, E1s, 64, 128, 128, 1, 1,
                 125, 125, 125, 125, 64, 1, 1, D1A, Bmu, Bs);
    launch_conv(Bmu, Bs, 125, 125, 64, 125, 125, 64, 1, 1, D1B, Amu, As);
    // ---- final 1x1 + softmax prop ----
    {
        int totalPix = B * 125 * 125;
        final_kernel<<<dim3((totalPix + 255) / 256), dim3(256), 0, stream>>>(
            Amu, As, wmu[FIN], wsig[FIN], (float*)d_out, B, 125, 125, 64);
    }
}